// Round 6
// baseline (2992.626 us; speedup 1.0000x reference)
//
#include <hip/hip_runtime.h>

typedef _Float16 f16_t;
typedef _Float16 f16x8 __attribute__((ext_vector_type(8)));
typedef float floatx4 __attribute__((ext_vector_type(4)));
typedef float floatx16 __attribute__((ext_vector_type(16)));

#define GLDS16(gptr, lptr) __builtin_amdgcn_global_load_lds( \
    (const __attribute__((address_space(1))) void*)(gptr),   \
    (__attribute__((address_space(3))) void*)(lptr), 16, 0, 0)

__device__ __forceinline__ float sigmoidf_fast(float x) {
    return 1.f / (1.f + __expf(-x));
}
__device__ __forceinline__ float tanhf_fast(float x) {
    float e = __expf(2.f * x);
    return 1.f - 2.f / (e + 1.f);
}

// giF layout (32x32 C/D tiles): off = ((g*256 + tM)*64 + tN)*1024 + lane*16 + r

// ---------------------------------------------------------------------------
__global__ __launch_bounds__(256)
void cvt_f32_f16(const float* __restrict__ in, f16_t* __restrict__ out, long n)
{
    long i = ((long)blockIdx.x * 256 + threadIdx.x) * 8;
    if (i >= n) return;
    floatx4 a = *(const floatx4*)(in + i);
    floatx4 b = *(const floatx4*)(in + i + 4);
    f16x8 o;
    o[0] = (f16_t)a[0]; o[1] = (f16_t)a[1]; o[2] = (f16_t)a[2]; o[3] = (f16_t)a[3];
    o[4] = (f16_t)b[0]; o[5] = (f16_t)b[1]; o[6] = (f16_t)b[2]; o[7] = (f16_t)b[3];
    *(f16x8*)(out + i) = o;
}

// ---------------------------------------------------------------------------
// gi = x @ w_ih^T + b_ih (3 gates, fragment-tiled) FUSED with iteration 1
// (h0=0 => gh=b_hh): epilogue computes h1 and writes h16 row-major.
// BM=128, BN=64/gate, BK=64, 32x32x16 MFMA. 8-slot XOR swizzle LDS.
// ---------------------------------------------------------------------------
__global__ __launch_bounds__(256, 3)
void gemm_gi32(const f16_t* __restrict__ Xh,   // 8192 x 2048
               const f16_t* __restrict__ Wih,  // 6144 x 2048
               const float* __restrict__ bih,  // 6144
               const float* __restrict__ bhh,  // 6144
               f16_t* __restrict__ giF,        // fragment-tiled
               f16_t* __restrict__ h16out)     // 8192 x 2048
{
    const int K = 2048, H = 2048;
    __shared__ __align__(16) f16_t smem[128 * 64 + 3 * 64 * 64];  // 40 KiB
    f16_t* As  = smem;
    f16_t* Wsm = smem + 128 * 64;
    const int tid  = threadIdx.x;
    const int lane = tid & 63;
    const int wave = tid >> 6;

    const int bid  = blockIdx.x;
    const int xcd  = bid & 7;
    const int rblk = bid >> 3;
    const int m0 = (rblk >> 2) * 128;
    const int n0 = (xcd * 4 + (rblk & 3)) * 64;

    const int wm = (wave >> 1) * 64;
    const int wn = (wave & 1) * 32;

    floatx16 acc[3][2] = {};

    const int srow8 = lane >> 3;
    const int sgk   = ((lane & 7) ^ srow8) * 8;
    const int c31   = lane & 31;
    const int half  = lane >> 5;

    for (int k0 = 0; k0 < K; k0 += 64) {
        #pragma unroll
        for (int j = 0; j < 4; ++j) {
            int c = j * 4 + wave;
            int row = c * 8 + srow8;
            GLDS16(Xh + (size_t)(m0 + row) * K + k0 + sgk, As + c * 512);
        }
        #pragma unroll
        for (int j = 0; j < 6; ++j) {
            int c = j * 4 + wave;
            int g = c >> 3;
            int cw = c & 7;
            int row = cw * 8 + srow8;
            GLDS16(Wih + (size_t)(g * H + n0 + row) * K + k0 + sgk,
                   Wsm + c * 512);
        }
        __syncthreads();

        #pragma unroll
        for (int ksub = 0; ksub < 4; ++ksub) {
            int gk = ksub * 2 + half;
            f16x8 a_frag[2];
            #pragma unroll
            for (int tm = 0; tm < 2; ++tm) {
                int row = wm + tm * 32 + c31;
                int slot = gk ^ (row & 7);
                a_frag[tm] = *(const f16x8*)(As + row * 64 + slot * 8);
            }
            #pragma unroll
            for (int g = 0; g < 3; ++g) {
                int row_w = wn + c31;
                int slot = gk ^ (row_w & 7);
                f16x8 b_frag = *(const f16x8*)(Wsm + g * 4096 +
                                               row_w * 64 + slot * 8);
                #pragma unroll
                for (int tm = 0; tm < 2; ++tm)
                    acc[g][tm] = __builtin_amdgcn_mfma_f32_32x32x16_f16(
                        a_frag[tm], b_frag, acc[g][tm], 0, 0, 0);
            }
        }
        __syncthreads();
    }

    // epilogue: write giF (gi + b_ih) and h1 = (1-z)*tanh(gn + r*b_hn)
    const int n   = n0 + wn + c31;
    const int tN  = (n0 + wn) >> 5;
    const int rhi = half * 4;
    const float br = bhh[n], bz = bhh[H + n], bnn = bhh[2 * H + n];
    const float bir = bih[n], biz = bih[H + n], bin = bih[2 * H + n];
    f16_t* hp = smem;   // reuse; all LDS reads done (post final barrier)
    #pragma unroll
    for (int tm = 0; tm < 2; ++tm) {
        int tM = (m0 + wm + tm * 32) >> 5;
        f16x8 s[3][2];
        #pragma unroll
        for (int r = 0; r < 16; ++r) {
            float gr = acc[0][tm][r] + bir;
            float gz = acc[1][tm][r] + biz;
            float gn = acc[2][tm][r] + bin;
            if (r < 8) {
                s[0][0][r] = (f16_t)gr; s[1][0][r] = (f16_t)gz; s[2][0][r] = (f16_t)gn;
            } else {
                s[0][1][r-8] = (f16_t)gr; s[1][1][r-8] = (f16_t)gz; s[2][1][r-8] = (f16_t)gn;
            }
            float rr = sigmoidf_fast(gr + br);
            float zz = sigmoidf_fast(gz + bz);
            float nn = tanhf_fast(gn + rr * bnn);
            float h = (1.f - zz) * nn;
            int ml = wm + tm * 32 + (r & 3) + 8 * (r >> 2) + rhi;
            hp[ml * 72 + wn + c31] = (f16_t)h;
        }
        #pragma unroll
        for (int g = 0; g < 3; ++g) {
            size_t off = ((size_t)(g * 256 + tM) * 64 + tN) * 1024 + lane * 16;
            *(f16x8*)(giF + off)     = s[g][0];
            *(f16x8*)(giF + off + 8) = s[g][1];
        }
    }
    __syncthreads();
    #pragma unroll
    for (int i = 0; i < 4; ++i) {
        int r2 = i * 32 + (tid >> 3);
        int ch = tid & 7;
        f16x8 v = *(const f16x8*)(hp + r2 * 72 + ch * 8);
        *(f16x8*)(h16out + (size_t)(m0 + r2) * H + n0 + ch * 8) = v;
    }
}

// ---------------------------------------------------------------------------
// Fused gh-GEMM (3 gates) + GRU update, 32x32x16 MFMA.
// BM=128, BN=64, BK=64. h_prev captured from As tile at k0==n0.
// Final iteration writes fp32 out via LDS transpose (float4 stores).
// ---------------------------------------------------------------------------
__global__ __launch_bounds__(256, 3)
void gru_step32(const f16_t* __restrict__ Wh,
                const float* __restrict__ bhh,
                const f16_t* __restrict__ giF,
                const f16_t* __restrict__ hin,
                f16_t* __restrict__ hout,
                float* __restrict__ out32)
{
    const int K = 2048, H = 2048;
    __shared__ __align__(16) f16_t smem[128 * 64 + 3 * 64 * 64];  // 40 KiB
    f16_t* As  = smem;
    f16_t* Wsm = smem + 128 * 64;
    const int tid  = threadIdx.x;
    const int lane = tid & 63;
    const int wave = tid >> 6;

    const int bid  = blockIdx.x;
    const int xcd  = bid & 7;
    const int rblk = bid >> 3;
    const int m0 = (rblk >> 2) * 128;
    const int n0 = (xcd * 4 + (rblk & 3)) * 64;

    const int wm = (wave >> 1) * 64;
    const int wn = (wave & 1) * 32;

    floatx16 acc[3][2] = {};

    const int srow8 = lane >> 3;
    const int sgk   = ((lane & 7) ^ srow8) * 8;
    const int c31   = lane & 31;
    const int half  = lane >> 5;
    const int rhi   = half * 4;
    const int kloc  = wn + c31;        // h column within As when k0==n0

    f16_t hold[2][16];

    for (int k0 = 0; k0 < K; k0 += 64) {
        #pragma unroll
        for (int j = 0; j < 4; ++j) {
            int c = j * 4 + wave;
            int row = c * 8 + srow8;
            GLDS16(hin + (size_t)(m0 + row) * K + k0 + sgk, As + c * 512);
        }
        #pragma unroll
        for (int j = 0; j < 6; ++j) {
            int c = j * 4 + wave;
            int g = c >> 3;
            int cw = c & 7;
            int row = cw * 8 + srow8;
            GLDS16(Wh + (size_t)(g * H + n0 + row) * K + k0 + sgk,
                   Wsm + c * 512);
        }
        __syncthreads();

        if (k0 == n0) {   // wave-uniform: capture h_prev fragment from As
            #pragma unroll
            for (int tm = 0; tm < 2; ++tm)
                #pragma unroll
                for (int r = 0; r < 16; ++r) {
                    int ml = wm + tm * 32 + (r & 3) + 8 * (r >> 2) + rhi;
                    int slot = (kloc >> 3) ^ (ml & 7);
                    hold[tm][r] = As[ml * 64 + slot * 8 + (kloc & 7)];
                }
        }

        #pragma unroll
        for (int ksub = 0; ksub < 4; ++ksub) {
            int gk = ksub * 2 + half;
            f16x8 a_frag[2];
            #pragma unroll
            for (int tm = 0; tm < 2; ++tm) {
                int row = wm + tm * 32 + c31;
                int slot = gk ^ (row & 7);
                a_frag[tm] = *(const f16x8*)(As + row * 64 + slot * 8);
            }
            #pragma unroll
            for (int g = 0; g < 3; ++g) {
                int row_w = wn + c31;
                int slot = gk ^ (row_w & 7);
                f16x8 b_frag = *(const f16x8*)(Wsm + g * 4096 +
                                               row_w * 64 + slot * 8);
                #pragma unroll
                for (int tm = 0; tm < 2; ++tm)
                    acc[g][tm] = __builtin_amdgcn_mfma_f32_32x32x16_f16(
                        a_frag[tm], b_frag, acc[g][tm], 0, 0, 0);
            }
        }
        __syncthreads();
    }

    // epilogue
    const int n  = n0 + wn + c31;
    const int tN = (n0 + wn) >> 5;
    const float br = bhh[n], bz = bhh[H + n], bnn = bhh[2 * H + n];
    f16_t* hp   = smem;
    float* hp32 = (float*)smem;
    #pragma unroll
    for (int tm = 0; tm < 2; ++tm) {
        int tM = (m0 + wm + tm * 32) >> 5;
        f16x8 glo[3], ghi[3];
        #pragma unroll
        for (int g = 0; g < 3; ++g) {
            size_t off = ((size_t)(g * 256 + tM) * 64 + tN) * 1024 + lane * 16;
            glo[g] = *(const f16x8*)(giF + off);
            ghi[g] = *(const f16x8*)(giF + off + 8);
        }
        #pragma unroll
        for (int r = 0; r < 16; ++r) {
            float gir = (float)((r < 8) ? glo[0][r] : ghi[0][r - 8]);
            float giz = (float)((r < 8) ? glo[1][r] : ghi[1][r - 8]);
            float gin = (float)((r < 8) ? glo[2][r] : ghi[2][r - 8]);
            float rr = sigmoidf_fast(gir + acc[0][tm][r] + br);
            float zz = sigmoidf_fast(giz + acc[1][tm][r] + bz);
            float nn = tanhf_fast(gin + rr * (acc[2][tm][r] + bnn));
            float hnew = (1.f - zz) * nn + zz * (float)hold[tm][r];
            int ml = wm + tm * 32 + (r & 3) + 8 * (r >> 2) + rhi;
            if (out32) hp32[ml * 68 + wn + c31] = hnew;
            else       hp[ml * 72 + wn + c31]   = (f16_t)hnew;
        }
    }
    __syncthreads();
    if (out32) {
        #pragma unroll
        for (int i = 0; i < 8; ++i) {
            int r2 = i * 16 + (tid >> 4);
            int c4 = (tid & 15) * 4;
            floatx4 v = *(const floatx4*)(hp32 + r2 * 68 + c4);
            *(floatx4*)(out32 + (size_t)(m0 + r2) * H + n0 + c4) = v;
        }
    } else {
        #pragma unroll
        for (int i = 0; i < 4; ++i) {
            int r2 = i * 32 + (tid >> 3);
            int ch = tid & 7;
            f16x8 v = *(const f16x8*)(hp + r2 * 72 + ch * 8);
            *(f16x8*)(hout + (size_t)(m0 + r2) * H + n0 + ch * 8) = v;
        }
    }
}

extern "C" void kernel_launch(void* const* d_in, const int* in_sizes, int n_in,
                              void* d_out, int out_size, void* d_ws, size_t ws_size,
                              hipStream_t stream) {
    const float* x    = (const float*)d_in[0];
    const float* w_ih = (const float*)d_in[1];
    const float* w_hh = (const float*)d_in[2];
    const float* b_ih = (const float*)d_in[3];
    const float* b_hh = (const float*)d_in[4];
    float* out = (float*)d_out;

    char* ws = (char*)d_ws;
    f16_t* xh    = (f16_t*)(ws);
    f16_t* wih_h = (f16_t*)(ws + 33554432);
    f16_t* whh_h = (f16_t*)(ws + 33554432 + 25165824);
    f16_t* gi    = (f16_t*)(ws + 33554432 + 2 * 25165824);
    f16_t* h16a  = (f16_t*)(ws + 33554432 + 2 * 25165824 + 100663296);
    f16_t* h16b  = (f16_t*)(ws + 33554432 + 2 * 25165824 + 100663296 + 33554432);

    cvt_f32_f16<<<dim3(8192), 256, 0, stream>>>(x, xh, 16777216L);
    cvt_f32_f16<<<dim3(6144), 256, 0, stream>>>(w_ih, wih_h, 12582912L);
    cvt_f32_f16<<<dim3(6144), 256, 0, stream>>>(w_hh, whh_h, 12582912L);

    // iteration 1 fused into the gi GEMM
    gemm_gi32<<<dim3(2048), 256, 0, stream>>>(xh, wih_h, b_ih, b_hh, gi, h16a);

    // iterations 2..10
    f16_t* hin = h16a; f16_t* hout = h16b;
    for (int it = 2; it <= 10; ++it) {
        float* o32 = (it == 10) ? out : nullptr;
        gru_step32<<<dim3(2048), 256, 0, stream>>>(whh_h, b_hh, gi,
                                                   hin, hout, o32);
        f16_t* t = hin; hin = hout; hout = t;
    }
}